// Round 1
// baseline (1076.068 us; speedup 1.0000x reference)
//
#include <hip/hip_runtime.h>

// LSTM: SEQ=4096 steps, BATCH=4096 independent chains, IN=2, HID=8, fp32.
// Layout: 32 lanes per batch element (one lane per gate row). 256-thr blocks
// hold 8 batch elems; grid = 512 blocks -> 2048 waves = 2 waves/SIMD.
// All cross-lane traffic is intra-32-lane-group (intra-wave): LDS ops from
// one wave execute in issue order, so no __syncthreads() is needed.

#define SEQ   4096
#define BATCH 4096
#define GPB   8     // batch elements (32-lane groups) per 256-thread block
#define PF    4     // x prefetch depth (steps)

__global__ __launch_bounds__(256) void lstm_kernel(
    const float* __restrict__ x,    // (SEQ, BATCH, 2)
    const float* __restrict__ h0,   // (1, BATCH, 8)
    const float* __restrict__ c0,   // (1, BATCH, 8)
    const float* __restrict__ Wih,  // (32, 2)
    const float* __restrict__ Whh,  // (32, 8)
    const float* __restrict__ bih,  // (32)
    const float* __restrict__ bhh,  // (32)
    float* __restrict__ out)        // (1, BATCH, 8)
{
    __shared__ float sAct[GPB][32];
    __shared__ float sH[GPB][8];

    const int tid = threadIdx.x;
    const int grp = tid >> 5;       // group within block (batch elem)
    const int g   = tid & 31;       // gate row 0..31  (i:0-7 f:8-15 g:16-23 o:24-31)
    const int j   = g & 7;          // hidden unit this lane's quad shares
    const int q   = g >> 3;         // gate quad: 0=i 1=f 2=g~ 3=o
    const int b   = blockIdx.x * GPB + grp;

    // Per-lane constant weights (live in VGPRs for the whole kernel)
    const float wa   = Wih[2 * g];
    const float wb   = Wih[2 * g + 1];
    const float bias = bih[g] + bhh[g];
    const float wh0 = Whh[8 * g + 0], wh1 = Whh[8 * g + 1];
    const float wh2 = Whh[8 * g + 2], wh3 = Whh[8 * g + 3];
    const float wh4 = Whh[8 * g + 4], wh5 = Whh[8 * g + 5];
    const float wh6 = Whh[8 * g + 6], wh7 = Whh[8 * g + 7];

    // Fused activation constants: sigmoid(x) = 1/(1+exp2(-x*log2e));
    // tanh(x) = 2*sigmoid(2x)-1. Lane's quad selects which.
    const float LOG2E = 1.4426950408889634f;
    const float tm    = (q == 2) ? 2.0f : 1.0f;
    const float addc  = 1.0f - tm;          // 0 for sigmoid, -1 for tanh
    const float smul  = -LOG2E * tm;
    const float cmul  = -2.0f * LOG2E;      // for tanh(c_new)

    // State: c replicated across the 4 lanes sharing hidden unit j;
    // full h vector replicated in every lane's registers (hA/hB).
    float c = c0[b * 8 + j];
    float4 hA = *(const float4*)(h0 + b * 8);
    float4 hB = *(const float4*)(h0 + b * 8 + 4);

    const float2* xp = (const float2*)x + b;   // xp[s*BATCH] = x[s][b][0:2]
    float2 xbuf[PF];
#pragma unroll
    for (int p = 0; p < PF; ++p) xbuf[p] = xp[(size_t)p * BATCH];

    float h = 0.0f;

    for (int s = 0; s < SEQ; s += PF) {
#pragma unroll
        for (int p = 0; p < PF; ++p) {
            const float2 xc = xbuf[p];
            int sn = s + p + PF;               // prefetch step index (clamped)
            sn = (sn < SEQ) ? sn : (SEQ - 1);
            xbuf[p] = xp[(size_t)sn * BATCH];

            // gate pre-activation: bias + x·Wih_row + h·Whh_row (2 FMA chains)
            float e0 = __builtin_fmaf(xc.x, wa, bias);
            e0 = __builtin_fmaf(xc.y, wb, e0);
            float e1 = hA.y * wh1;
            e0 = __builtin_fmaf(hA.x, wh0, e0);
            e1 = __builtin_fmaf(hA.z, wh2, e1);
            e0 = __builtin_fmaf(hA.w, wh3, e0);
            e1 = __builtin_fmaf(hB.x, wh4, e1);
            e0 = __builtin_fmaf(hB.y, wh5, e0);
            e1 = __builtin_fmaf(hB.z, wh6, e1);
            e0 = __builtin_fmaf(hB.w, wh7, e0);
            const float pre = e0 + e1;

            // fused sigmoid/tanh: one v_exp + one v_rcp per lane
            const float t  = pre * smul;
            const float ex = __builtin_amdgcn_exp2f(t);
            const float r  = __builtin_amdgcn_rcpf(ex + 1.0f);
            const float act = __builtin_fmaf(r, tm, addc);

            // cross-gate exchange (intra-wave, in-order LDS)
            sAct[grp][g] = act;
            __builtin_amdgcn_wave_barrier();
            const float gi = sAct[grp][j];
            const float gf = sAct[grp][j + 8];
            const float gg = sAct[grp][j + 16];
            const float go = sAct[grp][j + 24];
            __builtin_amdgcn_wave_barrier();

            // c/h update (computed redundantly by all 4 quads — free in SIMT)
            c = __builtin_fmaf(gf, c, gi * gg);
            const float t2 = c * cmul;
            const float e2 = __builtin_amdgcn_exp2f(t2);
            const float r2 = __builtin_amdgcn_rcpf(e2 + 1.0f);
            const float th = __builtin_fmaf(2.0f, r2, -1.0f);
            h = go * th;

            // broadcast h back to all lanes (same-addr LDS reads = broadcast)
            sH[grp][j] = h;   // 4 lanes/addr, identical value
            __builtin_amdgcn_wave_barrier();
            hA = *(const float4*)&sH[grp][0];
            hB = *(const float4*)&sH[grp][4];
            __builtin_amdgcn_wave_barrier();
        }
    }

    // lanes 0..7 hold h for j = g
    if (g < 8) out[b * 8 + g] = h;
}

extern "C" void kernel_launch(void* const* d_in, const int* in_sizes, int n_in,
                              void* d_out, int out_size, void* d_ws, size_t ws_size,
                              hipStream_t stream) {
    const float* x   = (const float*)d_in[0];
    const float* h0  = (const float*)d_in[1];
    const float* c0  = (const float*)d_in[2];
    const float* Wih = (const float*)d_in[3];
    const float* Whh = (const float*)d_in[4];
    const float* bih = (const float*)d_in[5];
    const float* bhh = (const float*)d_in[6];
    float* out = (float*)d_out;

    dim3 grid(BATCH / GPB);   // 512 blocks
    dim3 block(256);          // 8 groups of 32 lanes
    hipLaunchKernelGGL(lstm_kernel, grid, block, 0, stream,
                       x, h0, c0, Wih, Whh, bih, bhh, out);
}